// Round 5
// baseline (293.588 us; speedup 1.0000x reference)
//
#include <hip/hip_runtime.h>
#include <math.h>

// ColorLoss: mean over (b,m) of min_n ||pred[b,m]-gt[b,n]||, B=4, M=N=8192, D=3.
// Exact grid NN: 16^3 cells (~2 pts/cell). k_query scans only the 27 clamped
// neighbor cells (rings 0-1) with 4 lanes/query; the exactness bound is
// "unscanned cell differs by >=2 in an index -> dist > H", so if best2 <= H^2
// the result is exact. The rare failures (P ~ 2.3e-4) are pushed to a list and
// finished by k_fix (wave-parallel brute force) -- no serial tail in k_query.

constexpr int B  = 4;
constexpr int M  = 8192;
constexpr int N  = 8192;
constexpr int BM = B * M;
constexpr int G  = 16;
constexpr int NC = G * G * G;          // 4096 cells
constexpr float H = 1.0f / G;

__device__ __forceinline__ int cell_of(float x) {
  int c = (int)(x * (float)G);
  return c < 0 ? 0 : (c > G - 1 ? G - 1 : c);
}

// One block per batch: count -> exclusive scan -> scatter (sorted pts + cell_start).
__global__ __launch_bounds__(1024)
void k_bin(const float* __restrict__ gt, float4* __restrict__ sorted,
           int* __restrict__ cell_start, int* __restrict__ fail_count,
           float* __restrict__ out)
{
  const int b = blockIdx.x, t = threadIdx.x;
  const int lane = t & 63, wv = t >> 6;
  if (b == 0 && t == 0) { out[0] = 0.0f; fail_count[0] = 0; }   // ws/out poisoned 0xAA
  __shared__ int cnt[NC];
  __shared__ int wtot[16];

  for (int c = t; c < NC; c += 1024) cnt[c] = 0;
  __syncthreads();

  float px[8], py[8], pz[8]; int pc[8];
  const float* g = gt + (size_t)b * N * 3;
#pragma unroll
  for (int i = 0; i < 8; ++i) {
    const int idx = t + i * 1024;
    px[i] = g[idx * 3 + 0];
    py[i] = g[idx * 3 + 1];
    pz[i] = g[idx * 3 + 2];
    pc[i] = (cell_of(pz[i]) * G + cell_of(py[i])) * G + cell_of(px[i]);
    atomicAdd(&cnt[pc[i]], 1);
  }
  __syncthreads();

  // exclusive scan of cnt[4096], 4 contiguous per thread
  const int i0 = 4 * t;
  int v0 = cnt[i0], v1 = cnt[i0 + 1], v2 = cnt[i0 + 2], v3 = cnt[i0 + 3];
  const int own = v0 + v1 + v2 + v3;
  int s = own;
  for (int off = 1; off < 64; off <<= 1) {
    int nb = __shfl_up(s, off, 64);
    if (lane >= off) s += nb;
  }
  if (lane == 63) wtot[wv] = s;
  __syncthreads();
  if (t == 0) {
    int run = 0;
#pragma unroll
    for (int w = 0; w < 16; ++w) { int x = wtot[w]; wtot[w] = run; run += x; }
  }
  __syncthreads();
  const int excl = s - own + wtot[wv];
  cnt[i0]     = excl;
  cnt[i0 + 1] = excl + v0;
  cnt[i0 + 2] = excl + v0 + v1;
  cnt[i0 + 3] = excl + v0 + v1 + v2;
  __syncthreads();

  int* cs = cell_start + b * (NC + 1);
  for (int c = t; c < NC; c += 1024) cs[c] = cnt[c];
  if (t == 0) cs[NC] = N;
  __syncthreads();

  float4* dst = sorted + (size_t)b * N;
#pragma unroll
  for (int i = 0; i < 8; ++i) {
    const int pos = atomicAdd(&cnt[pc[i]], 1);
    dst[pos] = make_float4(px[i], py[i], pz[i], 0.0f);
  }
}

// 4 lanes/query; lane l scans x-rows {l, l+4, l+8} of the 3x3x3 neighborhood.
// Uniform fast path only; failures (best2 > H^2) deferred to fail_list.
__global__ __launch_bounds__(256)
void k_query(const float* __restrict__ pred, const float4* __restrict__ sorted,
             const int* __restrict__ cell_start, int* __restrict__ fail_count,
             int* __restrict__ fail_list, float* __restrict__ out)
{
  const int tid = blockIdx.x * 256 + threadIdx.x;
  const int p = tid >> 2;                 // query index
  const int l = tid & 3;                  // lane in quad
  const int b = p >> 13;                  // / 8192
  const float* a = pred + (size_t)p * 3;
  const float ax = a[0], ay = a[1], az = a[2];
  const int qi = cell_of(ax), qj = cell_of(ay), qk = cell_of(az);
  const float4* pts = sorted + (size_t)b * N;
  const int* cs = cell_start + b * (NC + 1);
  const int x0  = qi - 1 < 0 ? 0 : qi - 1;
  const int x1e = (qi + 1 > G - 1 ? G - 1 : qi + 1) + 1;

  // row bounds up front (independent gathers overlap their latency)
  int rs[3], re[3];
#pragma unroll
  for (int j = 0; j < 3; ++j) {
    const int rr = l + 4 * j;
    if (rr < 9) {
      const int dz = rr / 3 - 1, dy = rr % 3 - 1;
      const int z = qk + dz < 0 ? 0 : (qk + dz > G - 1 ? G - 1 : qk + dz);
      const int y = qj + dy < 0 ? 0 : (qj + dy > G - 1 ? G - 1 : qj + dy);
      const int cb = (z * G + y) * G;
      rs[j] = cs[cb + x0];
      re[j] = cs[cb + x1e];
    } else { rs[j] = 0; re[j] = 0; }
  }

  float best2 = 3.0e38f;
#pragma unroll
  for (int j = 0; j < 3; ++j) {
    int i = rs[j];
    const int e = re[j];
    for (; i + 4 <= e; i += 4) {          // 4 independent gathers in flight
      const float4 q0 = pts[i], q1 = pts[i + 1], q2 = pts[i + 2], q3 = pts[i + 3];
      const float d0 = fmaf(ax - q0.x, ax - q0.x, fmaf(ay - q0.y, ay - q0.y, (az - q0.z) * (az - q0.z)));
      const float d1 = fmaf(ax - q1.x, ax - q1.x, fmaf(ay - q1.y, ay - q1.y, (az - q1.z) * (az - q1.z)));
      const float d2 = fmaf(ax - q2.x, ax - q2.x, fmaf(ay - q2.y, ay - q2.y, (az - q2.z) * (az - q2.z)));
      const float d3 = fmaf(ax - q3.x, ax - q3.x, fmaf(ay - q3.y, ay - q3.y, (az - q3.z) * (az - q3.z)));
      best2 = fminf(best2, fminf(fminf(d0, d1), fminf(d2, d3)));
    }
    for (; i < e; ++i) {
      const float4 q = pts[i];
      const float dx = ax - q.x, dy = ay - q.y, dz = az - q.z;
      best2 = fminf(best2, fmaf(dx, dx, fmaf(dy, dy, dz * dz)));
    }
  }

  // quad min (lanes l^1, l^2 stay inside the aligned quad)
  best2 = fminf(best2, __shfl_xor(best2, 1, 64));
  best2 = fminf(best2, __shfl_xor(best2, 2, 64));

  float val = 0.0f;
  if (l == 0) {
    if (best2 <= H * H) {
      val = sqrtf(best2) * (1.0f / BM);   // exact: no unscanned cell can beat H
    } else {
      fail_list[atomicAdd(fail_count, 1)] = p;   // rare (P ~ 2.3e-4): defer
    }
  }

  for (int off = 32; off; off >>= 1) val += __shfl_down(val, off, 64);
  __shared__ float wsum[4];
  if ((threadIdx.x & 63) == 0) wsum[threadIdx.x >> 6] = val;
  __syncthreads();
  if (threadIdx.x == 0) atomicAdd(out, wsum[0] + wsum[1] + wsum[2] + wsum[3]);
}

// Finish deferred queries: one wave per failure, brute force over the batch's
// 8192 sorted points (coalesced float4 loads, 128 iters/lane, wave shfl-min).
__global__ __launch_bounds__(256)
void k_fix(const float* __restrict__ pred, const float4* __restrict__ sorted,
           const int* __restrict__ fail_count, const int* __restrict__ fail_list,
           float* __restrict__ out)
{
  const int wv = threadIdx.x >> 6, lane = threadIdx.x & 63;
  const int cnt = fail_count[0];
  for (int f = wv; f < cnt; f += 4) {
    const int p = fail_list[f];
    const int b = p >> 13;
    const float* a = pred + (size_t)p * 3;
    const float ax = a[0], ay = a[1], az = a[2];
    const float4* pts = sorted + (size_t)b * N;
    float best2 = 3.0e38f;
#pragma unroll 4
    for (int i = lane; i < N; i += 64) {
      const float4 q = pts[i];
      const float dx = ax - q.x, dy = ay - q.y, dz = az - q.z;
      best2 = fminf(best2, fmaf(dx, dx, fmaf(dy, dy, dz * dz)));
    }
#pragma unroll
    for (int off = 32; off; off >>= 1)
      best2 = fminf(best2, __shfl_xor(best2, off, 64));
    if (lane == 0) atomicAdd(out, sqrtf(best2) * (1.0f / BM));
  }
}

// ---- brute-force fallback (tiny workspace only) --------------------------------
__global__ __launch_bounds__(256)
void k_brute(const float* __restrict__ pred, const float* __restrict__ gt,
             float* __restrict__ out)
{
  constexpr int TPB = 256, RPT = 8, PPB = TPB * RPT, MBLK = M / PPB;
  const int mb = blockIdx.x % MBLK, b = blockIdx.x / MBLK, t = threadIdx.x;
  __shared__ float4 tile[1024];
  float cx[RPT], cy[RPT], cz[RPT], mn[RPT];
  const int mbase = mb * PPB + t;
#pragma unroll
  for (int r = 0; r < RPT; ++r) {
    const float* a = pred + ((size_t)b * M + (mbase + r * TPB)) * 3;
    cx[r] = -2.0f * a[0]; cy[r] = -2.0f * a[1]; cz[r] = -2.0f * a[2];
    mn[r] = 3.0e38f;
  }
  for (int n0 = 0; n0 < N; n0 += 1024) {
    __syncthreads();
    for (int i = t; i < 1024; i += TPB) {
      const float* gp = gt + ((size_t)b * N + (n0 + i)) * 3;
      float gx = gp[0], gy = gp[1], gz = gp[2];
      tile[i] = make_float4(gx, gy, gz, fmaf(gx, gx, fmaf(gy, gy, gz * gz)));
    }
    __syncthreads();
#pragma unroll 2
    for (int n = 0; n < 1024; n += 2) {
      const float4 g0 = tile[n], g1 = tile[n + 1];
#pragma unroll
      for (int r = 0; r < RPT; ++r) {
        float s0 = fmaf(cx[r], g0.x, fmaf(cy[r], g0.y, fmaf(cz[r], g0.z, g0.w)));
        float s1 = fmaf(cx[r], g1.x, fmaf(cy[r], g1.y, fmaf(cz[r], g1.z, g1.w)));
        mn[r] = fminf(fminf(s0, s1), mn[r]);
      }
    }
  }
  float sum = 0.0f;
#pragma unroll
  for (int r = 0; r < RPT; ++r) {
    const float* a = pred + ((size_t)b * M + (mbase + r * TPB)) * 3;
    float a2 = fmaf(a[0], a[0], fmaf(a[1], a[1], a[2] * a[2]));
    sum += sqrtf(fmaxf(a2 + mn[r], 0.0f)) * (1.0f / BM);
  }
  for (int off = 32; off; off >>= 1) sum += __shfl_down(sum, off, 64);
  __shared__ float wsum[4];
  if ((t & 63) == 0) wsum[t >> 6] = sum;
  __syncthreads();
  if (t == 0) atomicAdd(out, wsum[0] + wsum[1] + wsum[2] + wsum[3]);
}

extern "C" void kernel_launch(void* const* d_in, const int* in_sizes, int n_in,
                              void* d_out, int out_size, void* d_ws, size_t ws_size,
                              hipStream_t stream)
{
  const float* pred = (const float*)d_in[0];
  const float* gt   = (const float*)d_in[1];
  float* out = (float*)d_out;

  const size_t sz_sorted = (size_t)B * N * sizeof(float4);          // 512 KB
  const size_t sz_cs     = (size_t)B * (NC + 1) * sizeof(int);      // ~64 KB
  const size_t sz_fc     = 16;
  const size_t sz_fl     = (size_t)BM * sizeof(int);                // 128 KB
  if (ws_size >= sz_sorted + sz_cs + sz_fc + sz_fl) {
    char* w = (char*)d_ws;
    float4* sorted  = (float4*)w;                 w += sz_sorted;
    int* cell_start = (int*)w;                    w += sz_cs;
    int* fail_count = (int*)w;                    w += sz_fc;
    int* fail_list  = (int*)w;
    k_bin<<<dim3(B), dim3(1024), 0, stream>>>(gt, sorted, cell_start, fail_count, out);
    k_query<<<dim3(BM * 4 / 256), dim3(256), 0, stream>>>(pred, sorted, cell_start,
                                                          fail_count, fail_list, out);
    k_fix<<<dim3(1), dim3(256), 0, stream>>>(pred, sorted, fail_count, fail_list, out);
  } else {
    hipMemsetAsync(out, 0, sizeof(float), stream);
    k_brute<<<dim3(B * (M / 2048)), dim3(256), 0, stream>>>(pred, gt, out);
  }
}

// Round 6
// 82.041 us; speedup vs baseline: 3.5785x; 3.5785x over previous
//
#include <hip/hip_runtime.h>
#include <math.h>

// ColorLoss: mean over (b,m) of min_n ||pred[b,m]-gt[b,n]||, B=4, M=N=8192, D=3.
// Exact grid NN: 16^3 cells (~2 pts/cell). k_query scans only the 27 clamped
// neighbor cells (rings 0-1) with 4 lanes/query; exactness bound: any unscanned
// cell differs by >=2 in an index -> its points are > H away, so best2 <= H^2
// is provably exact. Failures (~110 of 32768, mostly near the domain walls
// where the H-ball is truncated) are deferred to a list and finished by k_fix:
// ONE BLOCK PER FAILURE (round-5 lesson: 1-block k_fix serialized to 260us).

constexpr int B  = 4;
constexpr int M  = 8192;
constexpr int N  = 8192;
constexpr int BM = B * M;
constexpr int G  = 16;
constexpr int NC = G * G * G;          // 4096 cells
constexpr float H = 1.0f / G;

__device__ __forceinline__ int cell_of(float x) {
  int c = (int)(x * (float)G);
  return c < 0 ? 0 : (c > G - 1 ? G - 1 : c);
}

// One block per batch: count -> exclusive scan -> scatter (sorted pts + cell_start).
__global__ __launch_bounds__(1024)
void k_bin(const float* __restrict__ gt, float4* __restrict__ sorted,
           int* __restrict__ cell_start, int* __restrict__ fail_count,
           float* __restrict__ out)
{
  const int b = blockIdx.x, t = threadIdx.x;
  const int lane = t & 63, wv = t >> 6;
  if (b == 0 && t == 0) { out[0] = 0.0f; fail_count[0] = 0; }   // ws/out poisoned 0xAA
  __shared__ int cnt[NC];
  __shared__ int wtot[16];

  for (int c = t; c < NC; c += 1024) cnt[c] = 0;
  __syncthreads();

  float px[8], py[8], pz[8]; int pc[8];
  const float* g = gt + (size_t)b * N * 3;
#pragma unroll
  for (int i = 0; i < 8; ++i) {
    const int idx = t + i * 1024;
    px[i] = g[idx * 3 + 0];
    py[i] = g[idx * 3 + 1];
    pz[i] = g[idx * 3 + 2];
    pc[i] = (cell_of(pz[i]) * G + cell_of(py[i])) * G + cell_of(px[i]);
    atomicAdd(&cnt[pc[i]], 1);
  }
  __syncthreads();

  // exclusive scan of cnt[4096], 4 contiguous per thread
  const int i0 = 4 * t;
  int v0 = cnt[i0], v1 = cnt[i0 + 1], v2 = cnt[i0 + 2], v3 = cnt[i0 + 3];
  const int own = v0 + v1 + v2 + v3;
  int s = own;
  for (int off = 1; off < 64; off <<= 1) {
    int nb = __shfl_up(s, off, 64);
    if (lane >= off) s += nb;
  }
  if (lane == 63) wtot[wv] = s;
  __syncthreads();
  if (t == 0) {
    int run = 0;
#pragma unroll
    for (int w = 0; w < 16; ++w) { int x = wtot[w]; wtot[w] = run; run += x; }
  }
  __syncthreads();
  const int excl = s - own + wtot[wv];
  cnt[i0]     = excl;
  cnt[i0 + 1] = excl + v0;
  cnt[i0 + 2] = excl + v0 + v1;
  cnt[i0 + 3] = excl + v0 + v1 + v2;
  __syncthreads();

  int* cs = cell_start + b * (NC + 1);
  for (int c = t; c < NC; c += 1024) cs[c] = cnt[c];
  if (t == 0) cs[NC] = N;
  __syncthreads();

  float4* dst = sorted + (size_t)b * N;
#pragma unroll
  for (int i = 0; i < 8; ++i) {
    const int pos = atomicAdd(&cnt[pc[i]], 1);
    dst[pos] = make_float4(px[i], py[i], pz[i], 0.0f);
  }
}

// 4 lanes/query; lane l scans x-rows {l, l+4, l+8} of the 3x3x3 neighborhood.
// Uniform fast path only; failures (best2 > H^2) deferred to fail_list.
__global__ __launch_bounds__(256)
void k_query(const float* __restrict__ pred, const float4* __restrict__ sorted,
             const int* __restrict__ cell_start, int* __restrict__ fail_count,
             int* __restrict__ fail_list, float* __restrict__ out)
{
  const int tid = blockIdx.x * 256 + threadIdx.x;
  const int p = tid >> 2;                 // query index
  const int l = tid & 3;                  // lane in quad
  const int b = p >> 13;                  // / 8192
  const float* a = pred + (size_t)p * 3;
  const float ax = a[0], ay = a[1], az = a[2];
  const int qi = cell_of(ax), qj = cell_of(ay), qk = cell_of(az);
  const float4* pts = sorted + (size_t)b * N;
  const int* cs = cell_start + b * (NC + 1);
  const int x0  = qi - 1 < 0 ? 0 : qi - 1;
  const int x1e = (qi + 1 > G - 1 ? G - 1 : qi + 1) + 1;

  // row bounds up front (independent gathers overlap their latency)
  int rs[3], re[3];
#pragma unroll
  for (int j = 0; j < 3; ++j) {
    const int rr = l + 4 * j;
    if (rr < 9) {
      const int dz = rr / 3 - 1, dy = rr % 3 - 1;
      const int z = qk + dz < 0 ? 0 : (qk + dz > G - 1 ? G - 1 : qk + dz);
      const int y = qj + dy < 0 ? 0 : (qj + dy > G - 1 ? G - 1 : qj + dy);
      const int cb = (z * G + y) * G;
      rs[j] = cs[cb + x0];
      re[j] = cs[cb + x1e];
    } else { rs[j] = 0; re[j] = 0; }
  }

  float best2 = 3.0e38f;
#pragma unroll
  for (int j = 0; j < 3; ++j) {
    int i = rs[j];
    const int e = re[j];
    for (; i + 4 <= e; i += 4) {          // 4 independent gathers in flight
      const float4 q0 = pts[i], q1 = pts[i + 1], q2 = pts[i + 2], q3 = pts[i + 3];
      const float d0 = fmaf(ax - q0.x, ax - q0.x, fmaf(ay - q0.y, ay - q0.y, (az - q0.z) * (az - q0.z)));
      const float d1 = fmaf(ax - q1.x, ax - q1.x, fmaf(ay - q1.y, ay - q1.y, (az - q1.z) * (az - q1.z)));
      const float d2 = fmaf(ax - q2.x, ax - q2.x, fmaf(ay - q2.y, ay - q2.y, (az - q2.z) * (az - q2.z)));
      const float d3 = fmaf(ax - q3.x, ax - q3.x, fmaf(ay - q3.y, ay - q3.y, (az - q3.z) * (az - q3.z)));
      best2 = fminf(best2, fminf(fminf(d0, d1), fminf(d2, d3)));
    }
    for (; i < e; ++i) {
      const float4 q = pts[i];
      const float dx = ax - q.x, dy = ay - q.y, dz = az - q.z;
      best2 = fminf(best2, fmaf(dx, dx, fmaf(dy, dy, dz * dz)));
    }
  }

  // quad min (lanes l^1, l^2 stay inside the aligned quad)
  best2 = fminf(best2, __shfl_xor(best2, 1, 64));
  best2 = fminf(best2, __shfl_xor(best2, 2, 64));

  float val = 0.0f;
  if (l == 0) {
    if (best2 <= H * H) {
      val = sqrtf(best2) * (1.0f / BM);   // exact: no unscanned cell can beat H
    } else {
      fail_list[atomicAdd(fail_count, 1)] = p;   // rare: defer to k_fix
    }
  }

  for (int off = 32; off; off >>= 1) val += __shfl_down(val, off, 64);
  __shared__ float wsum[4];
  if ((threadIdx.x & 63) == 0) wsum[threadIdx.x >> 6] = val;
  __syncthreads();
  if (threadIdx.x == 0) atomicAdd(out, wsum[0] + wsum[1] + wsum[2] + wsum[3]);
}

// Finish deferred queries: ONE BLOCK per failure (grid-strided), 256 threads
// brute-force the batch's 8192 sorted points: 32 float4/thread, unroll-4 ->
// 8 independent 4-load batches in flight; wave shfl-min -> LDS -> block min.
__global__ __launch_bounds__(256)
void k_fix(const float* __restrict__ pred, const float4* __restrict__ sorted,
           const int* __restrict__ fail_count, const int* __restrict__ fail_list,
           float* __restrict__ out)
{
  const int cnt = fail_count[0];
  __shared__ float wmin[4];
  for (int f = blockIdx.x; f < cnt; f += gridDim.x) {
    const int p = fail_list[f];
    const int b = p >> 13;
    const float* a = pred + (size_t)p * 3;
    const float ax = a[0], ay = a[1], az = a[2];
    const float4* pts = sorted + (size_t)b * N;
    float best2 = 3.0e38f;
#pragma unroll 4
    for (int i = threadIdx.x; i < N; i += 256) {
      const float4 q = pts[i];
      const float dx = ax - q.x, dy = ay - q.y, dz = az - q.z;
      best2 = fminf(best2, fmaf(dx, dx, fmaf(dy, dy, dz * dz)));
    }
#pragma unroll
    for (int off = 32; off; off >>= 1)
      best2 = fminf(best2, __shfl_xor(best2, off, 64));
    if ((threadIdx.x & 63) == 0) wmin[threadIdx.x >> 6] = best2;
    __syncthreads();
    if (threadIdx.x == 0) {
      const float m = fminf(fminf(wmin[0], wmin[1]), fminf(wmin[2], wmin[3]));
      atomicAdd(out, sqrtf(m) * (1.0f / BM));
    }
    __syncthreads();   // protect wmin before next grid-stride iteration
  }
}

// ---- brute-force fallback (tiny workspace only) --------------------------------
__global__ __launch_bounds__(256)
void k_brute(const float* __restrict__ pred, const float* __restrict__ gt,
             float* __restrict__ out)
{
  constexpr int TPB = 256, RPT = 8, PPB = TPB * RPT, MBLK = M / PPB;
  const int mb = blockIdx.x % MBLK, b = blockIdx.x / MBLK, t = threadIdx.x;
  __shared__ float4 tile[1024];
  float cx[RPT], cy[RPT], cz[RPT], mn[RPT];
  const int mbase = mb * PPB + t;
#pragma unroll
  for (int r = 0; r < RPT; ++r) {
    const float* a = pred + ((size_t)b * M + (mbase + r * TPB)) * 3;
    cx[r] = -2.0f * a[0]; cy[r] = -2.0f * a[1]; cz[r] = -2.0f * a[2];
    mn[r] = 3.0e38f;
  }
  for (int n0 = 0; n0 < N; n0 += 1024) {
    __syncthreads();
    for (int i = t; i < 1024; i += TPB) {
      const float* gp = gt + ((size_t)b * N + (n0 + i)) * 3;
      float gx = gp[0], gy = gp[1], gz = gp[2];
      tile[i] = make_float4(gx, gy, gz, fmaf(gx, gx, fmaf(gy, gy, gz * gz)));
    }
    __syncthreads();
#pragma unroll 2
    for (int n = 0; n < 1024; n += 2) {
      const float4 g0 = tile[n], g1 = tile[n + 1];
#pragma unroll
      for (int r = 0; r < RPT; ++r) {
        float s0 = fmaf(cx[r], g0.x, fmaf(cy[r], g0.y, fmaf(cz[r], g0.z, g0.w)));
        float s1 = fmaf(cx[r], g1.x, fmaf(cy[r], g1.y, fmaf(cz[r], g1.z, g1.w)));
        mn[r] = fminf(fminf(s0, s1), mn[r]);
      }
    }
  }
  float sum = 0.0f;
#pragma unroll
  for (int r = 0; r < RPT; ++r) {
    const float* a = pred + ((size_t)b * M + (mbase + r * TPB)) * 3;
    float a2 = fmaf(a[0], a[0], fmaf(a[1], a[1], a[2] * a[2]));
    sum += sqrtf(fmaxf(a2 + mn[r], 0.0f)) * (1.0f / BM);
  }
  for (int off = 32; off; off >>= 1) sum += __shfl_down(sum, off, 64);
  __shared__ float wsum[4];
  if ((t & 63) == 0) wsum[t >> 6] = sum;
  __syncthreads();
  if (t == 0) atomicAdd(out, wsum[0] + wsum[1] + wsum[2] + wsum[3]);
}

extern "C" void kernel_launch(void* const* d_in, const int* in_sizes, int n_in,
                              void* d_out, int out_size, void* d_ws, size_t ws_size,
                              hipStream_t stream)
{
  const float* pred = (const float*)d_in[0];
  const float* gt   = (const float*)d_in[1];
  float* out = (float*)d_out;

  const size_t sz_sorted = (size_t)B * N * sizeof(float4);          // 512 KB
  const size_t sz_cs     = (size_t)B * (NC + 1) * sizeof(int);      // ~64 KB
  const size_t sz_fc     = 16;
  const size_t sz_fl     = (size_t)BM * sizeof(int);                // 128 KB
  if (ws_size >= sz_sorted + sz_cs + sz_fc + sz_fl) {
    char* w = (char*)d_ws;
    float4* sorted  = (float4*)w;                 w += sz_sorted;
    int* cell_start = (int*)w;                    w += sz_cs;
    int* fail_count = (int*)w;                    w += sz_fc;
    int* fail_list  = (int*)w;
    k_bin<<<dim3(B), dim3(1024), 0, stream>>>(gt, sorted, cell_start, fail_count, out);
    k_query<<<dim3(BM * 4 / 256), dim3(256), 0, stream>>>(pred, sorted, cell_start,
                                                          fail_count, fail_list, out);
    k_fix<<<dim3(256), dim3(256), 0, stream>>>(pred, sorted, fail_count, fail_list, out);
  } else {
    hipMemsetAsync(out, 0, sizeof(float), stream);
    k_brute<<<dim3(B * (M / 2048)), dim3(256), 0, stream>>>(pred, gt, out);
  }
}